// Round 2
// baseline (160.062 us; speedup 1.0000x reference)
//
#include <hip/hip_runtime.h>
#include <hip/hip_bf16.h>
#include <math.h>
#include <cstdint>

#define FEPS 1e-8f
#define NBLK 2048
#define NTHR 256
#define CAND_CAP 4096

// ---------- numeric helpers ----------

// monotonic float -> uint mapping (order-preserving, ascending)
__device__ __forceinline__ uint32_t f2k(float f) {
    uint32_t b = __float_as_uint(f);
    return (b & 0x80000000u) ? ~b : (b | 0x80000000u);
}

// fast path: device logf (faithful ~1ulp)
__device__ __forceinline__ float gum_fast(float u) {
    float t = u + FEPS;
    float a = logf(t);
    float w = -a + FEPS;
    float d = logf(w);
    return -d;
}

// correctly-rounded f32 log via f64 log
__device__ __forceinline__ float logCR(float x) {
    return (float)log((double)x);
}
__device__ __forceinline__ float gum_cr(float u) {
    float t = u + FEPS;
    float a = logCR(t);
    float w = -a + FEPS;
    float d = logCR(w);
    return -d;
}

// exact decision for the 2-way gumbel-softmax argmax:
// out = 1  iff  RN(v1 - v0) > 2^-25   (exp(v0-v1) rounds to 1.0f otherwise,
// making softmax values equal and argmax pick index 0)
__device__ __forceinline__ float decide_cr(float maskv, float ua, float ub) {
    float G0 = gum_cr(ua);
    float G1 = gum_cr(ub);
    float V1 = maskv + G1;
    float diff = V1 - G0;
    return (diff > 0x1p-25f) ? 1.0f : 0.0f;
}
__device__ __forceinline__ float decide_tr(float maskv, float ua, float ub) {
    float g0 = gum_fast(ua);
    float g1 = gum_fast(ub);
    float v1 = maskv + g1;
    float diff = v1 - g0;
    if (fabsf(diff) > 1e-4f) return (diff > 0.0f) ? 1.0f : 0.0f;
    return decide_cr(maskv, ua, ub);
}

// ---------- K0: zero workspace ----------
__global__ void k_zero(uint32_t* __restrict__ hist1, uint32_t* __restrict__ hist2,
                       uint32_t* __restrict__ scal, uint32_t* __restrict__ candCount) {
    int i = blockIdx.x * blockDim.x + threadIdx.x;
    int stride = gridDim.x * blockDim.x;
    for (int b = i; b < 4096; b += stride) hist1[b] = 0u;
    for (int b = i; b < (1 << 20); b += stride) hist2[b] = 0u;
    if (i < 16) scal[i] = 0u;
    if (i == 0) *candCount = 0u;
}

// ---------- K1: compute keys (into d_out) + 12-bit histogram ----------
__global__ void __launch_bounds__(NTHR) k_keys(
        const float* __restrict__ lg, const float* __restrict__ u1,
        const int* __restrict__ trainp, uint32_t* __restrict__ keys,
        uint32_t* __restrict__ hist1, int N) {
    __shared__ uint32_t h[4096];
    for (int b = threadIdx.x; b < 4096; b += blockDim.x) h[b] = 0u;
    __syncthreads();
    const int tr = *trainp;
    const int n4 = N >> 2;
    const int tid = blockIdx.x * blockDim.x + threadIdx.x;
    const int stride = gridDim.x * blockDim.x;
    for (int i = tid; i < n4; i += stride) {
        float4 m = ((const float4*)lg)[i];
        float4 u = ((const float4*)u1)[i];
        float z0, z1, z2, z3;
        if (tr) {
            z0 = m.x + gum_fast(u.x);
            z1 = m.y + gum_fast(u.y);
            z2 = m.z + gum_fast(u.z);
            z3 = m.w + gum_fast(u.w);
        } else { z0 = m.x; z1 = m.y; z2 = m.z; z3 = m.w; }
        uint4 kk = make_uint4(f2k(z0), f2k(z1), f2k(z2), f2k(z3));
        ((uint4*)keys)[i] = kk;
        atomicAdd(&h[kk.x >> 20], 1u);
        atomicAdd(&h[kk.y >> 20], 1u);
        atomicAdd(&h[kk.z >> 20], 1u);
        atomicAdd(&h[kk.w >> 20], 1u);
    }
    for (int i = (n4 << 2) + tid; i < N; i += stride) {  // tail
        float m = lg[i], u = u1[i];
        float z = tr ? (m + gum_fast(u)) : m;
        uint32_t kx = f2k(z);
        keys[i] = kx;
        atomicAdd(&h[kx >> 20], 1u);
    }
    __syncthreads();
    for (int b = threadIdx.x; b < 4096; b += blockDim.x) {
        uint32_t v = h[b];
        if (v) atomicAdd(&hist1[b], v);
    }
}

// ---------- K2: scan 4096 bins from top, find bin b1 ----------
__global__ void __launch_bounds__(1024) k_scan1(
        const uint32_t* __restrict__ hist1, const int* __restrict__ kptr,
        uint32_t* __restrict__ scal) {
    __shared__ uint32_t vals[4096];
    __shared__ uint32_t cnt[1024];
    const int t = threadIdx.x;
    uint32_t loc = 0;
    for (int j = 0; j < 4; j++) {
        uint32_t v = hist1[4095 - (t * 4 + j)];
        vals[t * 4 + j] = v;
        loc += v;
    }
    cnt[t] = loc;
    __syncthreads();
    for (int off = 1; off < 1024; off <<= 1) {
        uint32_t add = (t >= off) ? cnt[t - off] : 0u;
        __syncthreads();
        cnt[t] += add;
        __syncthreads();
    }
    const uint32_t K = (uint32_t)(*kptr);
    uint32_t excl = (t > 0) ? cnt[t - 1] : 0u;
    uint32_t incl = cnt[t];
    if (excl < K && K <= incl) {
        uint32_t c = excl;
        for (int j = 0; j < 4; j++) {
            uint32_t v = vals[t * 4 + j];
            if (K <= c + v) {
                scal[0] = (uint32_t)(4095 - (t * 4 + j));  // b1
                scal[1] = K - c;                            // kk1: needed inside bin b1
                scal[2] = c;                                // total_gt: count in bins above b1
                break;
            }
            c += v;
        }
    }
}

// ---------- K3: 20-bit histogram of elements in bin b1 ----------
__global__ void __launch_bounds__(NTHR) k_hist2(
        const uint32_t* __restrict__ keys, const uint32_t* __restrict__ scal,
        uint32_t* __restrict__ hist2, int N) {
    const uint32_t b1 = scal[0];
    const int n4 = N >> 2;
    const int tid = blockIdx.x * blockDim.x + threadIdx.x;
    const int stride = gridDim.x * blockDim.x;
    for (int i = tid; i < n4; i += stride) {
        uint4 kk = ((const uint4*)keys)[i];
        if ((kk.x >> 20) == b1) atomicAdd(&hist2[kk.x & 0xFFFFFu], 1u);
        if ((kk.y >> 20) == b1) atomicAdd(&hist2[kk.y & 0xFFFFFu], 1u);
        if ((kk.z >> 20) == b1) atomicAdd(&hist2[kk.z & 0xFFFFFu], 1u);
        if ((kk.w >> 20) == b1) atomicAdd(&hist2[kk.w & 0xFFFFFu], 1u);
    }
    for (int i = (n4 << 2) + tid; i < N; i += stride) {
        uint32_t kx = keys[i];
        if ((kx >> 20) == b1) atomicAdd(&hist2[kx & 0xFFFFFu], 1u);
    }
}

// ---------- K4a: chunk partial sums of hist2 (1024 chunks of 1024) ----------
__global__ void __launch_bounds__(NTHR) k_part(
        const uint32_t* __restrict__ hist2, uint32_t* __restrict__ part) {
    __shared__ uint32_t red[NTHR];
    uint32_t sum = 0;
    const int base = blockIdx.x << 10;
    for (int j = threadIdx.x; j < 1024; j += NTHR) sum += hist2[base + j];
    red[threadIdx.x] = sum;
    __syncthreads();
    for (int off = NTHR / 2; off; off >>= 1) {
        if (threadIdx.x < off) red[threadIdx.x] += red[threadIdx.x + off];
        __syncthreads();
    }
    if (threadIdx.x == 0) part[blockIdx.x] = red[0];
}

// ---------- K4b: find exact threshold, window [klo,khi], count above window ----------
__global__ void __launch_bounds__(1024) k_scan2(
        const uint32_t* __restrict__ hist2, const uint32_t* __restrict__ part,
        uint32_t* __restrict__ scal) {
    __shared__ uint32_t cs[1024];
    __shared__ uint32_t bs[1024];
    __shared__ uint32_t red[1024];
    __shared__ int shI[4];
    const int t = threadIdx.x;
    const uint32_t b1 = scal[0];
    const uint32_t kk1 = scal[1];
    const uint32_t total_gt = scal[2];

    // reversed inclusive scan over chunk partials
    cs[t] = part[1023 - t];
    __syncthreads();
    for (int off = 1; off < 1024; off <<= 1) {
        uint32_t add = (t >= off) ? cs[t - off] : 0u;
        __syncthreads();
        cs[t] += add;
        __syncthreads();
    }
    {
        uint32_t excl = t ? cs[t - 1] : 0u;
        if (excl < kk1 && kk1 <= cs[t]) shI[0] = t;
    }
    __syncthreads();
    const int rp = shI[0];
    const int jc = 1023 - rp;
    const uint32_t gt_chunks = rp ? cs[rp - 1] : 0u;
    const uint32_t kk_in = kk1 - gt_chunks;

    // reversed inclusive scan over bins of chunk jc
    bs[t] = hist2[(jc << 10) + (1023 - t)];
    __syncthreads();
    for (int off = 1; off < 1024; off <<= 1) {
        uint32_t add = (t >= off) ? bs[t - off] : 0u;
        __syncthreads();
        bs[t] += add;
        __syncthreads();
    }
    {
        uint32_t excl = t ? bs[t - 1] : 0u;
        if (excl < kk_in && kk_in <= bs[t]) shI[1] = t;
    }
    __syncthreads();
    const int rq = shI[1];
    const int b2 = (jc << 10) + (1023 - rq);  // low-20 bits of threshold key

    // window of +-W ulps (clamped to bin b1), shrink if pathologically populated
    int W = 64;
    int lo = 0, hi = 0;
    uint32_t caw = 0;
    while (true) {
        lo = b2 - W; if (lo < 0) lo = 0;
        hi = b2 + W; if (hi > 0xFFFFF) hi = 0xFFFFF;
        uint32_t v = 0;
        for (int b = lo + t; b <= hi; b += 1024) v += hist2[b];
        red[t] = v;
        __syncthreads();
        for (int off = 512; off; off >>= 1) {
            if (t < off) red[t] += red[t + off];
            __syncthreads();
        }
        uint32_t nW = red[0];
        __syncthreads();
        if (nW <= 3500u || W == 0) {
            const int ch = hi >> 10;
            const int chend = (ch << 10) + 1023;
            uint32_t v2 = 0;
            for (int b = hi + 1 + t; b <= chend; b += 1024) v2 += hist2[b];
            red[t] = v2;
            __syncthreads();
            for (int off = 512; off; off >>= 1) {
                if (t < off) red[t] += red[t + off];
                __syncthreads();
            }
            uint32_t inpart = red[0];
            __syncthreads();
            const int rpch = 1023 - ch;
            const uint32_t sufExcl = rpch ? cs[rpch - 1] : 0u;
            caw = total_gt + sufExcl + inpart;  // count of keys strictly above window
            break;
        }
        W >>= 1;
    }
    if (t == 0) {
        scal[3] = (b1 << 20) | (uint32_t)lo;  // klo
        scal[4] = (b1 << 20) | (uint32_t)hi;  // khi
        scal[5] = caw;
    }
}

// ---------- K7: final pass — decide all non-window elements, collect window candidates ----------
// NOTE: keys live in d_out; this kernel reads key then overwrites with result (same address,
// read-before-write within thread; window elements left for k_refine).
__global__ void __launch_bounds__(NTHR) k_final(
        uint32_t* __restrict__ keys /* == (uint32_t*)d_out */,
        const float* __restrict__ u2, const int* __restrict__ trainp,
        const uint32_t* __restrict__ scal,
        uint32_t* __restrict__ candIdx, uint32_t* __restrict__ candCount, int N) {
    const uint32_t klo = scal[3], khi = scal[4];
    const int tr = *trainp;
    const int n4 = N >> 2;
    const int tid = blockIdx.x * blockDim.x + threadIdx.x;
    const int stride = gridDim.x * blockDim.x;
    float* outf = (float*)keys;
    for (int i = tid; i < n4; i += stride) {
        uint4 kk = ((const uint4*)keys)[i];
        uint32_t ks[4] = {kk.x, kk.y, kk.z, kk.w};
        float uu[8];
        if (tr) {
            float4 ua = ((const float4*)u2)[2 * i];
            float4 ub = ((const float4*)u2)[2 * i + 1];
            uu[0] = ua.x; uu[1] = ua.y; uu[2] = ua.z; uu[3] = ua.w;
            uu[4] = ub.x; uu[5] = ub.y; uu[6] = ub.z; uu[7] = ub.w;
        }
        float res[4];
        bool inw[4];
        bool anyw = false;
        #pragma unroll
        for (int j = 0; j < 4; j++) {
            inw[j] = (ks[j] >= klo) && (ks[j] <= khi);
            anyw |= inw[j];
        }
        #pragma unroll
        for (int j = 0; j < 4; j++) {
            float mv = (ks[j] > khi) ? 1.0f : 0.0f;
            res[j] = (tr && !inw[j]) ? decide_tr(mv, uu[2 * j], uu[2 * j + 1]) : mv;
        }
        if (!anyw) {
            ((float4*)outf)[i] = make_float4(res[0], res[1], res[2], res[3]);
        } else {
            #pragma unroll
            for (int j = 0; j < 4; j++) {
                if (inw[j]) {
                    uint32_t p = atomicAdd(candCount, 1u);
                    if (p < CAND_CAP) candIdx[p] = (uint32_t)(4 * i + j);
                } else {
                    outf[4 * i + j] = res[j];
                }
            }
        }
    }
    for (int i = (n4 << 2) + tid; i < N; i += stride) {  // tail
        uint32_t kx = keys[i];
        if (kx >= klo && kx <= khi) {
            uint32_t p = atomicAdd(candCount, 1u);
            if (p < CAND_CAP) candIdx[p] = (uint32_t)i;
            continue;
        }
        float mv = (kx > khi) ? 1.0f : 0.0f;
        outf[i] = tr ? decide_tr(mv, u2[2 * i], u2[2 * i + 1]) : mv;
    }
}

// ---------- K8: refine window candidates exactly (CR log, sort, select) ----------
__global__ void __launch_bounds__(NTHR) k_refine(
        const float* __restrict__ lg, const float* __restrict__ u1,
        const float* __restrict__ u2, const int* __restrict__ kptr,
        const int* __restrict__ trainp, const uint32_t* __restrict__ scal,
        const uint32_t* __restrict__ candIdx, const uint32_t* __restrict__ candCount,
        float* __restrict__ out) {
    __shared__ float zs[CAND_CAP];
    __shared__ int is[CAND_CAP];
    const int tr = *trainp;
    int n = (int)(*candCount);
    if (n > CAND_CAP) n = CAND_CAP;
    int npow2 = 64;
    while (npow2 < n) npow2 <<= 1;

    for (int e = threadIdx.x; e < npow2; e += NTHR) {
        if (e < n) {
            int i = (int)candIdx[e];
            float m = lg[i];
            zs[e] = tr ? (m + gum_cr(u1[i])) : m;
            is[e] = i;
        } else {
            zs[e] = -INFINITY;
            is[e] = 0x40000000 + e;
        }
    }
    __syncthreads();

    // bitonic sort: descending by z, ascending by index on ties (matches lax.top_k)
    for (int size = 2; size <= npow2; size <<= 1) {
        for (int str = size >> 1; str > 0; str >>= 1) {
            for (int e = threadIdx.x; e < npow2; e += NTHR) {
                int p = e ^ str;
                if (p > e) {
                    float za = zs[e], zb = zs[p];
                    int ia = is[e], ib = is[p];
                    bool aBefore = (za > zb) || (za == zb && ia < ib);
                    bool descBlock = ((e & size) == 0);
                    if (descBlock ? !aBefore : aBefore) {
                        zs[e] = zb; zs[p] = za;
                        is[e] = ib; is[p] = ia;
                    }
                }
            }
            __syncthreads();
        }
    }

    const int K = *kptr;
    const int caw = (int)scal[5];
    const int R = K - caw;  // how many window elements are selected
    for (int e = threadIdx.x; e < n; e += NTHR) {
        int i = is[e];
        float mv = (e < R) ? 1.0f : 0.0f;
        float o;
        if (tr) {
            o = decide_cr(mv, u2[2 * i], u2[2 * i + 1]);
        } else {
            o = mv;
        }
        out[i] = o;
    }
}

// ---------- launcher ----------
extern "C" void kernel_launch(void* const* d_in, const int* in_sizes, int n_in,
                              void* d_out, int out_size, void* d_ws, size_t ws_size,
                              hipStream_t stream) {
    const float* lg = (const float*)d_in[0];
    const float* u1 = (const float*)d_in[1];
    const float* u2 = (const float*)d_in[2];
    const int* kptr = (const int*)d_in[3];
    const int* trainp = (const int*)d_in[4];
    float* out = (float*)d_out;
    const int N = in_sizes[0];

    // keys are staged inside d_out (same size, uint32 view) and overwritten by results.
    uint32_t* keys = (uint32_t*)d_out;

    // small workspace (~4.2 MB)
    uint32_t* hist1 = (uint32_t*)d_ws;           // 4096
    uint32_t* hist2 = hist1 + 4096;              // 1<<20
    uint32_t* part = hist2 + (1u << 20);         // 1024
    uint32_t* scal = part + 1024;                // 16
    uint32_t* candCount = scal + 16;             // 1
    uint32_t* candIdx = candCount + 1;           // CAND_CAP

    k_zero<<<dim3(1024), dim3(256), 0, stream>>>(hist1, hist2, scal, candCount);
    k_keys<<<dim3(NBLK), dim3(NTHR), 0, stream>>>(lg, u1, trainp, keys, hist1, N);
    k_scan1<<<dim3(1), dim3(1024), 0, stream>>>(hist1, kptr, scal);
    k_hist2<<<dim3(NBLK), dim3(NTHR), 0, stream>>>(keys, scal, hist2, N);
    k_part<<<dim3(1024), dim3(NTHR), 0, stream>>>(hist2, part);
    k_scan2<<<dim3(1), dim3(1024), 0, stream>>>(hist2, part, scal);
    k_final<<<dim3(NBLK), dim3(NTHR), 0, stream>>>(keys, u2, trainp, scal, candIdx, candCount, N);
    k_refine<<<dim3(1), dim3(NTHR), 0, stream>>>(lg, u1, u2, kptr, trainp, scal, candIdx, candCount, out);
}